// Round 4
// baseline (1522.831 us; speedup 1.0000x reference)
//
#include <hip/hip_runtime.h>

#define TT 50
#define BB 512
#define II 784
#define HH 800
#define OO 10
#define BH (BB*HH)   // 409600
#define MM (TT*BB)   // 25600

typedef double d4 __attribute__((ext_vector_type(4)));

// Decode a probe-sum value back to a row/col index 0..15.
// Family 1 (holders {u, u+16, u+32, u+48}): V = 4u + 96  (V-96 ≡ 0 mod 4)
// Family 2 (holders {4u .. 4u+3}):          V = 16u + 6  (V-96 ≡ 2 mod 4)
__device__ __forceinline__ int dec16(double V) {
    const int vi = (int)(V + 0.5);
    const int a = vi - 96;
    if (a >= 0 && a < 64 && (a & 3) == 0) return a >> 2;
    return ((vi - 6) >> 4) & 15;
}
__device__ __forceinline__ bool isf1(double V) {
    const int vi = (int)(V + 0.5);
    const int a = vi - 96;
    return (a >= 0 && a < 64 && (a & 3) == 0);
}

// K-step compute: NS steps of 4 k each from one LDS buffer pair.
template<int NS>
__device__ __forceinline__ void gemm1_compute(
    const float* __restrict__ Ab, const float* __restrict__ Bb,
    int wm, int arow, int akk, int bcol, int bkk, d4 acc[2][5])
{
    #pragma unroll
    for (int s = 0; s < NS; ++s) {
        const int ka = 4*s + akk;
        const int kb = 4*s + bkk;
        const double a0d = (double)Ab[ka*144 + wm + arow];
        const double a1d = (double)Ab[ka*144 + wm + 16 + arow];
        double bd[5];
        #pragma unroll
        for (int j = 0; j < 5; ++j)
            bd[j] = (double)Bb[kb*80 + 16*j + bcol];
        #pragma unroll
        for (int j = 0; j < 5; ++j) {
            acc[0][j] = __builtin_amdgcn_mfma_f64_16x16x4f64(
                a0d, bd[j], acc[0][j], 0, 0, 0);
            acc[1][j] = __builtin_amdgcn_mfma_f64_16x16x4f64(
                a1d, bd[j], acc[1][j], 0, 0, 0);
        }
    }
}

// ---------------------------------------------------------------------------
// K1: x1d[m][n] = sum_k x[m][k]*W1[n][k] + b1[n], f64 via v_mfma_f64_16x16x4
// (order-safe: any f64 order matches ref's layer-1 exactly — R1/R3 proof).
// M=25600, N=800, K=784. Block tile 128m x 80n, grid 200 x 10, 4 waves.
// R3 counters: MfmaUtil 67%, occupancy 22% (2 blocks/CU, reg-bound — fixed).
// Residual idle = 2 barriers/chunk + serial LDS-store section + first-read
// latency, ~370 cyc/wave/chunk.  R4 FIX:
//   * KC=32 super-chunks (784 = 24*32 + 16 tail): 25 barriers total (was 98),
//     first-read latency amortized over 80 MFMAs.
//   * double-buffered LDS: stores for chunk c+1 issue DURING compute of
//     chunk c (other parity buffer) -> store section fully hidden; ONE
//     barrier per chunk.  Reg prefetch is a full compute phase (~1280 cyc)
//     ahead of its ds_write consumer.
// LDS 2x(32*144 + 32*80)*4 = 57.3 KB/block; 2 blocks/CU = 114.6 < 160 KB.
// LAYOUT SELF-CALIBRATION (proven R2): two probe MFMAs recover the true A/B
// lane->(row,k) feed split AND per-register C/D (row,col) positions.
// ---------------------------------------------------------------------------
__global__ __launch_bounds__(256) void k_gemm1(
    const float* __restrict__ x, const float* __restrict__ W1,
    const float* __restrict__ b1, double* __restrict__ x1d)
{
    __shared__ float As[2][32*144];   // [buf][k][m], stride 144
    __shared__ float Bs[2][32*80];    // [buf][k][n], stride 80
    const int m0 = blockIdx.x * 128;
    const int n0 = blockIdx.y * 80;
    const int tid = threadIdx.x;
    const int lane = tid & 63;
    const int wm = (tid >> 6) * 32;    // wave m-offset

    // ---- layout probes (2 MFMAs, negligible) ----
    const d4 zc = {0.0, 0.0, 0.0, 0.0};
    const d4 pr = __builtin_amdgcn_mfma_f64_16x16x4f64(
        (double)lane, 1.0, zc, 0, 0, 0);
    const d4 pc = __builtin_amdgcn_mfma_f64_16x16x4f64(
        1.0, (double)lane, zc, 0, 0, 0);
    int rowIdx[4], colIdx[4];
    #pragma unroll
    for (int r = 0; r < 4; ++r) {
        rowIdx[r] = dec16(pr[r]) & 15;
        colIdx[r] = dec16(pc[r]) & 15;
    }
    const bool af1 = isf1(pr[0]);
    const bool bf1 = isf1(pc[0]);
    const int arow = af1 ? (lane & 15) : (lane >> 2);
    const int akk  = af1 ? (lane >> 4) : (lane & 3);
    const int bcol = bf1 ? (lane & 15) : (lane >> 2);
    const int bkk  = bf1 ? (lane >> 4) : (lane & 3);

    d4 acc[2][5] = {};

    // Staging tasks (KC=32 chunk): float4 granularity, koff shared.
    //   A: 128 rows x 8 quads = 1024 tasks: row = (tid>>3)+32r (r=0..3)
    //   B:  80 rows x 8 quads =  640 tasks: row = (tid>>3)+32r (r=0..2,
    //       r=2 only tid<128)
    const int koff = (tid & 7) * 4;    // 0,4,...,28
    const int r0   = tid >> 3;         // 0..31
    const float* pA0 = x + (long)(m0 + r0      )*II + koff;
    const float* pA1 = x + (long)(m0 + r0 + 32 )*II + koff;
    const float* pA2 = x + (long)(m0 + r0 + 64 )*II + koff;
    const float* pA3 = x + (long)(m0 + r0 + 96 )*II + koff;
    const float* pB0 = W1 + (long)(n0 + r0     )*II + koff;
    const float* pB1 = W1 + (long)(n0 + r0 + 32)*II + koff;
    const int rB2 = (tid < 128) ? (r0 + 64) : 79;   // clamp keeps ptr in-bounds
    const float* pB2 = W1 + (long)(n0 + rB2)*II + koff;

    float4 RA0, RA1, RA2, RA3, RB0, RB1, RB2;

#define G1_LOAD(c) do {                                                  \
        const int _k0 = 32*(c);                                          \
        const int _kc = ((c) == 24) ? 16 : 32;                           \
        if (koff < _kc) {                                                \
            RA0 = *(const float4*)(pA0 + _k0);                           \
            RA1 = *(const float4*)(pA1 + _k0);                           \
            RA2 = *(const float4*)(pA2 + _k0);                           \
            RA3 = *(const float4*)(pA3 + _k0);                           \
            RB0 = *(const float4*)(pB0 + _k0);                           \
            RB1 = *(const float4*)(pB1 + _k0);                           \
            if (tid < 128) RB2 = *(const float4*)(pB2 + _k0);            \
        }                                                                \
    } while (0)

#define G1_STORE(c) do {                                                 \
        float* _Ad = As[(c) & 1];                                        \
        float* _Bd = Bs[(c) & 1];                                        \
        const int _kc = ((c) == 24) ? 16 : 32;                           \
        if (koff < _kc) {                                                \
            _Ad[(koff+0)*144 + r0      ] = RA0.x;                        \
            _Ad[(koff+1)*144 + r0      ] = RA0.y;                        \
            _Ad[(koff+2)*144 + r0      ] = RA0.z;                        \
            _Ad[(koff+3)*144 + r0      ] = RA0.w;                        \
            _Ad[(koff+0)*144 + r0 + 32 ] = RA1.x;                        \
            _Ad[(koff+1)*144 + r0 + 32 ] = RA1.y;                        \
            _Ad[(koff+2)*144 + r0 + 32 ] = RA1.z;                        \
            _Ad[(koff+3)*144 + r0 + 32 ] = RA1.w;                        \
            _Ad[(koff+0)*144 + r0 + 64 ] = RA2.x;                        \
            _Ad[(koff+1)*144 + r0 + 64 ] = RA2.y;                        \
            _Ad[(koff+2)*144 + r0 + 64 ] = RA2.z;                        \
            _Ad[(koff+3)*144 + r0 + 64 ] = RA2.w;                        \
            _Ad[(koff+0)*144 + r0 + 96 ] = RA3.x;                        \
            _Ad[(koff+1)*144 + r0 + 96 ] = RA3.y;                        \
            _Ad[(koff+2)*144 + r0 + 96 ] = RA3.z;                        \
            _Ad[(koff+3)*144 + r0 + 96 ] = RA3.w;                        \
            _Bd[(koff+0)*80 + r0       ] = RB0.x;                        \
            _Bd[(koff+1)*80 + r0       ] = RB0.y;                        \
            _Bd[(koff+2)*80 + r0       ] = RB0.z;                        \
            _Bd[(koff+3)*80 + r0       ] = RB0.w;                        \
            _Bd[(koff+0)*80 + r0 + 32  ] = RB1.x;                        \
            _Bd[(koff+1)*80 + r0 + 32  ] = RB1.y;                        \
            _Bd[(koff+2)*80 + r0 + 32  ] = RB1.z;                        \
            _Bd[(koff+3)*80 + r0 + 32  ] = RB1.w;                        \
            if (tid < 128) {                                             \
                _Bd[(koff+0)*80 + r0 + 64] = RB2.x;                      \
                _Bd[(koff+1)*80 + r0 + 64] = RB2.y;                      \
                _Bd[(koff+2)*80 + r0 + 64] = RB2.z;                      \
                _Bd[(koff+3)*80 + r0 + 64] = RB2.w;                      \
            }                                                            \
        }                                                                \
    } while (0)

    // prologue: fill buf0 with chunk 0, prefetch chunk 1 into regs
    G1_LOAD(0);
    G1_STORE(0);
    G1_LOAD(1);
    __syncthreads();

    for (int c = 0; c < 24; ++c) {          // full 32-k chunks
        G1_STORE(c + 1);                    // other-parity buffer: no wait
        if (c + 2 < 25) G1_LOAD(c + 2);     // 2 chunks ahead
        gemm1_compute<8>(As[c & 1], Bs[c & 1],
                         wm, arow, akk, bcol, bkk, acc);
        __syncthreads();                    // ONE barrier per chunk
    }
    // tail chunk 24 (16 k) sits in buf0
    gemm1_compute<4>(As[0], Bs[0], wm, arow, akk, bcol, bkk, acc);

#undef G1_LOAD
#undef G1_STORE

    #pragma unroll
    for (int i = 0; i < 2; ++i) {
        #pragma unroll
        for (int r = 0; r < 4; ++r) {
            const long m = m0 + wm + 16*i + rowIdx[r];
            #pragma unroll
            for (int j = 0; j < 5; ++j) {
                const int n = n0 + 16*j + colIdx[r];
                x1d[m*HH + n] = acc[i][j][r] + (double)b1[n];
            }
        }
    }
}

// ---------------------------------------------------------------------------
// K2: LIF scan layer 1, f64 (PROVEN path). Reads x1d; writes compact u8
// spikes (ws) + s1r f32 (d_out, write-only).
// ---------------------------------------------------------------------------
__global__ __launch_bounds__(256) void k_mem1(
    const double* __restrict__ x1d, const float* __restrict__ thresh1,
    unsigned char* __restrict__ s1c, float* __restrict__ s1r)
{
    const int lid = blockIdx.x*256 + threadIdx.x;   // = b*HH + h
    const int h = lid % HH;
    const double th = (double)thresh1[h];
    double mem = 0.0;
    for (int t = 0; t < TT; ++t) {
        const long idx = (long)t*BH + lid;
        mem = 0.95*mem + x1d[idx];
        const bool spk = mem > th;
        s1c[idx] = spk ? 1 : 0;
        s1r[idx] = spk ? 1.0f : 0.0f;
        if (spk) mem = 0.0;
    }
}

// ---------------------------------------------------------------------------
// K3: z2[m][n] = chain_k( s1[m][k]*W2[n][k] ) — strict ascending-k single
// __fmaf_rn chain per output (EXACT R5 layer-2 semantics; u8->f32 is exact).
// Tile 128m x 80n, KC=32, frag 8m(contig) x (4n contig + 1), grid 200x10.
// ---------------------------------------------------------------------------
__global__ __launch_bounds__(256) void k_gemm2(
    const unsigned char* __restrict__ s1c, const float* __restrict__ W2,
    float* __restrict__ z2)
{
    __shared__ float As[32*132];
    __shared__ float Bs[32*84];
    const int m0 = blockIdx.x * 128;
    const int n0 = blockIdx.y * 80;
    const int tid = threadIdx.x;
    const int tx = tid & 15, ty = tid >> 4;
    float acc[8][5] = {};

    const int sm = tid >> 1;          // 0..127
    const int sk = (tid & 1) * 16;    // 0 or 16
    // B: 80 rows x 32 k = 640 float4 tasks: tid, tid+256, tid+512(<128)
    const int b0n = tid >> 3,        b0k = (tid & 7) * 4;
    const int q1 = tid + 256, b1n = q1 >> 3, b1k = (q1 & 7) * 4;
    const int q2 = tid + 512, b2n = q2 >> 3, b2k = (q2 & 7) * 4;

    for (int k0 = 0; k0 < HH; k0 += 32) {   // 800 = 25*32
        const uint4 av = *(const uint4*)(s1c + (long)(m0+sm)*HH + k0 + sk);
        const float4 w0 = *(const float4*)(W2 + (long)(n0+b0n)*HH + k0 + b0k);
        const float4 w1 = *(const float4*)(W2 + (long)(n0+b1n)*HH + k0 + b1k);
        float4 w2;
        if (tid < 128)
            w2 = *(const float4*)(W2 + (long)(n0+b2n)*HH + k0 + b2k);
        __syncthreads();
        {
            const unsigned int d[4] = {av.x, av.y, av.z, av.w};
            #pragma unroll
            for (int w = 0; w < 4; ++w) {
                #pragma unroll
                for (int j = 0; j < 4; ++j)
                    As[(sk + w*4 + j)*132 + sm] =
                        (float)((d[w] >> (8*j)) & 0xffu);
            }
        }
        Bs[(b0k+0)*84+b0n] = w0.x; Bs[(b0k+1)*84+b0n] = w0.y;
        Bs[(b0k+2)*84+b0n] = w0.z; Bs[(b0k+3)*84+b0n] = w0.w;
        Bs[(b1k+0)*84+b1n] = w1.x; Bs[(b1k+1)*84+b1n] = w1.y;
        Bs[(b1k+2)*84+b1n] = w1.z; Bs[(b1k+3)*84+b1n] = w1.w;
        if (tid < 128) {
            Bs[(b2k+0)*84+b2n] = w2.x; Bs[(b2k+1)*84+b2n] = w2.y;
            Bs[(b2k+2)*84+b2n] = w2.z; Bs[(b2k+3)*84+b2n] = w2.w;
        }
        __syncthreads();
        #pragma unroll
        for (int k = 0; k < 32; ++k) {
            float a[8], b[5];
            #pragma unroll
            for (int i = 0; i < 8; ++i) a[i] = As[k*132 + ty*8 + i];
            #pragma unroll
            for (int j = 0; j < 4; ++j) b[j] = Bs[k*84 + tx*4 + j];
            b[4] = Bs[k*84 + 64 + tx];
            #pragma unroll
            for (int i = 0; i < 8; ++i)
                #pragma unroll
                for (int j = 0; j < 5; ++j)
                    acc[i][j] = __fmaf_rn(a[i], b[j], acc[i][j]);
        }
    }
    #pragma unroll
    for (int i = 0; i < 8; ++i) {
        const long m = m0 + ty*8 + i;
        #pragma unroll
        for (int j = 0; j < 4; ++j)
            z2[m*HH + n0 + tx*4 + j] = acc[i][j];
        z2[m*HH + n0 + 64 + tx] = acc[i][4];
    }
}

// ---------------------------------------------------------------------------
// K4: layer-2 membrane scan, strict fp32 np order ((0.95f*m)+z)+b2 (EXACT
// R5 semantics). mem2 in registers; writes s2r (d_out) + s2c (ws u8).
// ---------------------------------------------------------------------------
__global__ __launch_bounds__(256) void k_scan2(
    const float* __restrict__ z2, const float* __restrict__ b2,
    const float* __restrict__ thresh2, float* __restrict__ s2r,
    unsigned char* __restrict__ s2c)
{
    const int lid = blockIdx.x*256 + threadIdx.x;   // = b*HH + n
    const int n = lid % HH;
    const float b2v = b2[n];
    const float thv = thresh2[n];
    float m = 0.0f;
    for (int t = 0; t < TT; ++t) {
        const long idx = (long)t*BH + lid;
        const float m2 = __fadd_rn(
            __fadd_rn(__fmul_rn(0.95f, m), z2[idx]), b2v);
        const bool spk = m2 > thv;
        s2r[idx] = spk ? 1.0f : 0.0f;
        s2c[idx] = spk ? 1 : 0;
        m = spk ? 0.0f : m2;
    }
}

// ---------------------------------------------------------------------------
// K5: z3[m][o] = chain_k( s2[m][k]*W3[o][k] ) — strict ascending-k single
// chain (EXACT R5 layer-3 matmul semantics). One thread per m row, 10 accs;
// W3 accesses are wave-uniform -> scalar loads.
// ---------------------------------------------------------------------------
__global__ __launch_bounds__(256) void k_gemm3(
    const unsigned char* __restrict__ s2c, const float* __restrict__ W3,
    float* __restrict__ z3)
{
    const long m = blockIdx.x*256 + threadIdx.x;
    const unsigned char* row = s2c + m*HH;
    float acc[10] = {};
    for (int k0 = 0; k0 < HH; k0 += 16) {
        const uint4 v = *(const uint4*)(row + k0);
        const unsigned int d[4] = {v.x, v.y, v.z, v.w};
        #pragma unroll
        for (int w = 0; w < 4; ++w) {
            #pragma unroll
            for (int j = 0; j < 4; ++j) {
                const float sv = (float)((d[w] >> (8*j)) & 0xffu);
                const int k = k0 + w*4 + j;
                #pragma unroll
                for (int o = 0; o < 10; ++o)
                    acc[o] = __fmaf_rn(sv, W3[o*HH + k], acc[o]);
            }
        }
    }
    #pragma unroll
    for (int o = 0; o < 10; ++o)
        z3[m*OO + o] = acc[o];
}

// ---------------------------------------------------------------------------
// K6: layer-3 membrane scan, strict fp32 (EXACT R5 semantics). Writes s3r +
// out0 (d_out, write-only).
// ---------------------------------------------------------------------------
__global__ __launch_bounds__(256) void k_scan3(
    const float* __restrict__ z3, const float* __restrict__ b3,
    float* __restrict__ s3r, float* __restrict__ out0)
{
    const int gid = blockIdx.x*256 + threadIdx.x;   // = b*OO + o
    if (gid >= BB*OO) return;
    const int o = gid % OO;
    const float b3v = b3[o];
    float mem = 0.0f, cnt = 0.0f;
    for (int t = 0; t < TT; ++t) {
        const float m3 = __fadd_rn(
            __fadd_rn(__fmul_rn(0.95f, mem), z3[(long)t*BB*OO + gid]), b3v);
        const bool spk = m3 > 1.0f;
        s3r[(long)t*BB*OO + gid] = spk ? 1.0f : 0.0f;
        if (spk) cnt = __fadd_rn(cnt, 1.0f);
        mem = spk ? 0.0f : m3;
    }
    out0[gid] = cnt;
}

// ---------------------------------------------------------------------------
extern "C" void kernel_launch(void* const* d_in, const int* in_sizes, int n_in,
                              void* d_out, int out_size, void* d_ws, size_t ws_size,
                              hipStream_t stream)
{
    const float* x   = (const float*)d_in[0];
    const float* W1  = (const float*)d_in[1];
    const float* b1  = (const float*)d_in[2];
    const float* W2  = (const float*)d_in[3];
    const float* b2  = (const float*)d_in[4];
    const float* W3  = (const float*)d_in[5];
    const float* b3  = (const float*)d_in[6];
    const float* th1 = (const float*)d_in[7];
    const float* th2 = (const float*)d_in[8];

    float* out0 = (float*)d_out;                    // (B, OUT)   d_out is
    float* s1r  = out0 + BB*OO;                     // (T, B, H)  WRITE-ONLY
    float* s2r  = s1r + (long)TT*BH;                // (T, B, H)
    float* s3r  = s2r + (long)TT*BH;                // (T, B, OUT)

    // ws layout (total 204.8 MB == R5-proven budget):
    //   [0 .. 163.84 MB)   x1d f64  — dead after k_mem1, region reused:
    //        [0 .. 81.92 MB)      z2 f32  (written by k_gemm2 after k_mem1)
    //        [84 MB .. 85.03 MB)  z3 f32
    //   [163.84 .. 184.32 MB) s1c u8
    //   [184.32 .. 204.80 MB) s2c u8
    char* p = (char*)d_ws;
    double* x1d = (double*)p;
    float*  z2  = (float*)p;
    float*  z3  = (float*)(p + 84000000);
    unsigned char* s1c = (unsigned char*)(p + 163840000);
    unsigned char* s2c = s1c + (size_t)TT*BH;
    (void)ws_size;

    k_gemm1<<<dim3(200,10), dim3(256), 0, stream>>>(x, W1, b1, x1d);
    k_mem1 <<<dim3(1600),   dim3(256), 0, stream>>>(x1d, th1, s1c, s1r);
    k_gemm2<<<dim3(200,10), dim3(256), 0, stream>>>(s1c, W2, z2);
    k_scan2<<<dim3(1600),   dim3(256), 0, stream>>>(z2, b2, th2, s2r, s2c);
    k_gemm3<<<dim3(100),    dim3(256), 0, stream>>>(s2c, W3, z3);
    k_scan3<<<dim3(20),     dim3(256), 0, stream>>>(z3, b3, s3r, out0);
}

// Round 5
// 1336.664 us; speedup vs baseline: 1.1393x; 1.1393x over previous
//
#include <hip/hip_runtime.h>

#define TT 50
#define BB 512
#define II 784
#define HH 800
#define OO 10
#define BH (BB*HH)   // 409600
#define MM (TT*BB)   // 25600

typedef double d4 __attribute__((ext_vector_type(4)));

// Decode a probe-sum value back to a row/col index 0..15.
// Family 1 (holders {u, u+16, u+32, u+48}): V = 4u + 96  (V-96 ≡ 0 mod 4)
// Family 2 (holders {4u .. 4u+3}):          V = 16u + 6  (V-96 ≡ 2 mod 4)
__device__ __forceinline__ int dec16(double V) {
    const int vi = (int)(V + 0.5);
    const int a = vi - 96;
    if (a >= 0 && a < 64 && (a & 3) == 0) return a >> 2;
    return ((vi - 6) >> 4) & 15;
}
__device__ __forceinline__ bool isf1(double V) {
    const int vi = (int)(V + 0.5);
    const int a = vi - 96;
    return (a >= 0 && a < 64 && (a & 3) == 0);
}

// K-step compute: NS steps of 4 k each from one LDS buffer pair.
template<int NS>
__device__ __forceinline__ void gemm1_compute(
    const float* __restrict__ Ab, const float* __restrict__ Bb,
    int wm, int arow, int akk, int bcol, int bkk, d4 acc[2][5])
{
    #pragma unroll
    for (int s = 0; s < NS; ++s) {
        const int ka = 4*s + akk;
        const int kb = 4*s + bkk;
        const double a0d = (double)Ab[ka*144 + wm + arow];
        const double a1d = (double)Ab[ka*144 + wm + 16 + arow];
        double bd[5];
        #pragma unroll
        for (int j = 0; j < 5; ++j)
            bd[j] = (double)Bb[kb*80 + 16*j + bcol];
        #pragma unroll
        for (int j = 0; j < 5; ++j) {
            acc[0][j] = __builtin_amdgcn_mfma_f64_16x16x4f64(
                a0d, bd[j], acc[0][j], 0, 0, 0);
            acc[1][j] = __builtin_amdgcn_mfma_f64_16x16x4f64(
                a1d, bd[j], acc[1][j], 0, 0, 0);
        }
    }
}

// ---------------------------------------------------------------------------
// K1: x1d[m][n] = sum_k x[m][k]*W1[n][k] + b1[n], f64 via v_mfma_f64_16x16x4
// (order-safe: any f64 order matches ref's layer-1 exactly — R1/R3 proof).
// M=25600, N=800, K=784. Block tile 128m x 80n, grid 200 x 10, 4 waves.
// R4 POST-MORTEM: KC=32 restage broke staging-write bank pattern (8-way,
// conflicts 4x) AND 57KB LDS dropped residency to 1 block/CU -> 808us.
// R5: R3 base (proven 659us: KC=16, conflict-free staging, reg prefetch)
// + MINIMAL double-buffer: two 16-k LDS buffers (28.7KB, 2-block residency
// preserved), ONE barrier per chunk (49 vs 98):
//   STORE(c)->buf[c&1]; LOAD(c+1); barrier; COMPUTE(c) from buf[c&1].
// Safety: a wave storing chunk c passed barrier c-1 => all waves finished
// COMPUTE(c-2), the last reader of buf[c&1].  Stores now sit adjacent to
// compute (inter-wave slack absorbs them) instead of between two barriers.
// LAYOUT SELF-CALIBRATION (proven R2): two probe MFMAs recover the true A/B
// lane->(row,k) feed split AND per-register C/D (row,col) positions.
// ---------------------------------------------------------------------------
__global__ __launch_bounds__(256) void k_gemm1(
    const float* __restrict__ x, const float* __restrict__ W1,
    const float* __restrict__ b1, double* __restrict__ x1d)
{
    __shared__ float As[2][16*144];   // [buf][k][m], stride 144
    __shared__ float Bs[2][16*80];    // [buf][k][n], stride 80
    const int m0 = blockIdx.x * 128;
    const int n0 = blockIdx.y * 80;
    const int tid = threadIdx.x;
    const int lane = tid & 63;
    const int wm = (tid >> 6) * 32;    // wave m-offset

    // ---- layout probes (2 MFMAs, negligible) ----
    const d4 zc = {0.0, 0.0, 0.0, 0.0};
    const d4 pr = __builtin_amdgcn_mfma_f64_16x16x4f64(
        (double)lane, 1.0, zc, 0, 0, 0);
    const d4 pc = __builtin_amdgcn_mfma_f64_16x16x4f64(
        1.0, (double)lane, zc, 0, 0, 0);
    int rowIdx[4], colIdx[4];
    #pragma unroll
    for (int r = 0; r < 4; ++r) {
        rowIdx[r] = dec16(pr[r]) & 15;
        colIdx[r] = dec16(pc[r]) & 15;
    }
    const bool af1 = isf1(pr[0]);
    const bool bf1 = isf1(pc[0]);
    const int arow = af1 ? (lane & 15) : (lane >> 2);
    const int akk  = af1 ? (lane >> 4) : (lane & 3);
    const int bcol = bf1 ? (lane & 15) : (lane >> 2);
    const int bkk  = bf1 ? (lane >> 4) : (lane & 3);

    d4 acc[2][5] = {};

    // A staging (R3-proven, 2-way-free): row sm (0..127), k-offset sk (0/8)
    const int sm = tid >> 1;
    const int sk = (tid & 1) * 8;
    // B staging: 80n x 16k = 320 float4 tasks: tid (n 0..63), tid+256 (tid<64)
    const int bn0 = tid >> 2, bk0 = (tid & 3) * 4;
    const int q1  = tid + 256;
    const int bn1 = q1 >> 2,  bk1 = (q1 & 3) * 4;

    const float* aptr  = x  + (long)(m0+sm)*II + sk;
    const float* bptr0 = W1 + (long)(n0+bn0)*II + bk0;
    const float* bptr1 = W1 + (long)(n0+bn1)*II + bk1;

    // prefetch chunk 0
    float4 pa0 = *(const float4*)(aptr);
    float4 pa1 = *(const float4*)(aptr + 4);
    float4 pw0 = *(const float4*)(bptr0);
    float4 pw1;
    if (tid < 64) pw1 = *(const float4*)(bptr1);

    for (int c = 0; c < 49; ++c) {          // 784 = 49*16
        float* Ad = &As[c & 1][0];
        float* Bd = &Bs[c & 1][0];
        Ad[(sk+0)*144+sm] = pa0.x;
        Ad[(sk+1)*144+sm] = pa0.y;
        Ad[(sk+2)*144+sm] = pa0.z;
        Ad[(sk+3)*144+sm] = pa0.w;
        Ad[(sk+4)*144+sm] = pa1.x;
        Ad[(sk+5)*144+sm] = pa1.y;
        Ad[(sk+6)*144+sm] = pa1.z;
        Ad[(sk+7)*144+sm] = pa1.w;
        Bd[(bk0+0)*80+bn0] = pw0.x;
        Bd[(bk0+1)*80+bn0] = pw0.y;
        Bd[(bk0+2)*80+bn0] = pw0.z;
        Bd[(bk0+3)*80+bn0] = pw0.w;
        if (tid < 64) {
            Bd[(bk1+0)*80+bn1] = pw1.x;
            Bd[(bk1+1)*80+bn1] = pw1.y;
            Bd[(bk1+2)*80+bn1] = pw1.z;
            Bd[(bk1+3)*80+bn1] = pw1.w;
        }
        if (c + 1 < 49) {                   // prefetch next chunk; vmcnt wait
            const int k0 = (c + 1) * 16;    // lands at next iter's stores,
            pa0 = *(const float4*)(aptr + k0);      // hidden under MFMAs
            pa1 = *(const float4*)(aptr + k0 + 4);
            pw0 = *(const float4*)(bptr0 + k0);
            if (tid < 64) pw1 = *(const float4*)(bptr1 + k0);
        }
        __syncthreads();                    // ONE barrier per chunk
        gemm1_compute<4>(Ad, Bd, wm, arow, akk, bcol, bkk, acc);
    }

    #pragma unroll
    for (int i = 0; i < 2; ++i) {
        #pragma unroll
        for (int r = 0; r < 4; ++r) {
            const long m = m0 + wm + 16*i + rowIdx[r];
            #pragma unroll
            for (int j = 0; j < 5; ++j) {
                const int n = n0 + 16*j + colIdx[r];
                x1d[m*HH + n] = acc[i][j][r] + (double)b1[n];
            }
        }
    }
}

// ---------------------------------------------------------------------------
// K2: LIF scan layer 1, f64 (PROVEN path). Reads x1d; writes compact u8
// spikes (ws) + s1r f32 (d_out, write-only).
// ---------------------------------------------------------------------------
__global__ __launch_bounds__(256) void k_mem1(
    const double* __restrict__ x1d, const float* __restrict__ thresh1,
    unsigned char* __restrict__ s1c, float* __restrict__ s1r)
{
    const int lid = blockIdx.x*256 + threadIdx.x;   // = b*HH + h
    const int h = lid % HH;
    const double th = (double)thresh1[h];
    double mem = 0.0;
    for (int t = 0; t < TT; ++t) {
        const long idx = (long)t*BH + lid;
        mem = 0.95*mem + x1d[idx];
        const bool spk = mem > th;
        s1c[idx] = spk ? 1 : 0;
        s1r[idx] = spk ? 1.0f : 0.0f;
        if (spk) mem = 0.0;
    }
}

// ---------------------------------------------------------------------------
// K3: z2[m][n] = chain_k( s1[m][k]*W2[n][k] ) — strict ascending-k single
// __fmaf_rn chain per output (EXACT R5 layer-2 semantics; u8->f32 is exact).
// Tile 128m x 80n, frag 8m(contig) x (4n contig + 1), grid 200x10.
// R5: same dbuf+prefetch skeleton as k_gemm1 (KC=16, ONE barrier per chunk,
// 50 chunks). Inner fmaf chain, ascending-k order, epilogue UNCHANGED ->
// bit-exact.  LDS 2x(16*132+16*84)*4 = 27.6KB.
// A staging: uint2 (8 u8) per thread: row=tid>>1, koff=(tid&1)*8; unpack
// writes are 2-way bank aliased (132 ≡ 4 mod 32, even/odd lanes same sm) = free.
// ---------------------------------------------------------------------------
__global__ __launch_bounds__(256) void k_gemm2(
    const unsigned char* __restrict__ s1c, const float* __restrict__ W2,
    float* __restrict__ z2)
{
    __shared__ float As[2][16*132];
    __shared__ float Bs[2][16*84];
    const int m0 = blockIdx.x * 128;
    const int n0 = blockIdx.y * 80;
    const int tid = threadIdx.x;
    const int tx = tid & 15, ty = tid >> 4;
    float acc[8][5] = {};

    // A staging: row am (0..127), k-offset ak (0 or 8), uint2 = 8 u8
    const int am = tid >> 1;
    const int ak = (tid & 1) * 8;
    // B staging: 80n x 16k = 320 float4 tasks: tid (bn 0..63), tid+256 (tid<64)
    const int bn0 = tid >> 2, bk0 = (tid & 3) * 4;
    const int q1 = tid + 256;
    const int bn1 = q1 >> 2, bk1 = (q1 & 3) * 4;

    const unsigned char* ap = s1c + (long)(m0+am)*HH + ak;
    const float* bp0 = W2 + (long)(n0+bn0)*HH + bk0;
    const float* bp1 = W2 + (long)(n0+bn1)*HH + bk1;

    // prefetch chunk 0
    uint2 ra = *(const uint2*)(ap);
    float4 rb0 = *(const float4*)(bp0);
    float4 rb1;
    if (tid < 64) rb1 = *(const float4*)(bp1);

    for (int c = 0; c < 50; ++c) {        // 800 = 50*16
        float* Ad = &As[c & 1][0];
        float* Bd = &Bs[c & 1][0];
        {
            const unsigned int lo = ra.x, hi = ra.y;
            Ad[(ak+0)*132+am] = (float)( lo        & 0xffu);
            Ad[(ak+1)*132+am] = (float)((lo >>  8) & 0xffu);
            Ad[(ak+2)*132+am] = (float)((lo >> 16) & 0xffu);
            Ad[(ak+3)*132+am] = (float)((lo >> 24) & 0xffu);
            Ad[(ak+4)*132+am] = (float)( hi        & 0xffu);
            Ad[(ak+5)*132+am] = (float)((hi >>  8) & 0xffu);
            Ad[(ak+6)*132+am] = (float)((hi >> 16) & 0xffu);
            Ad[(ak+7)*132+am] = (float)((hi >> 24) & 0xffu);
        }
        Bd[(bk0+0)*84+bn0] = rb0.x;
        Bd[(bk0+1)*84+bn0] = rb0.y;
        Bd[(bk0+2)*84+bn0] = rb0.z;
        Bd[(bk0+3)*84+bn0] = rb0.w;
        if (tid < 64) {
            Bd[(bk1+0)*84+bn1] = rb1.x;
            Bd[(bk1+1)*84+bn1] = rb1.y;
            Bd[(bk1+2)*84+bn1] = rb1.z;
            Bd[(bk1+3)*84+bn1] = rb1.w;
        }
        if (c + 1 < 50) {
            const int k0 = (c + 1) * 16;
            ra = *(const uint2*)(ap + k0);
            rb0 = *(const float4*)(bp0 + k0);
            if (tid < 64) rb1 = *(const float4*)(bp1 + k0);
        }
        __syncthreads();                    // ONE barrier per chunk
        #pragma unroll
        for (int k = 0; k < 16; ++k) {
            float a[8], b[5];
            #pragma unroll
            for (int i = 0; i < 8; ++i) a[i] = Ad[k*132 + ty*8 + i];
            #pragma unroll
            for (int j = 0; j < 4; ++j) b[j] = Bd[k*84 + tx*4 + j];
            b[4] = Bd[k*84 + 64 + tx];
            #pragma unroll
            for (int i = 0; i < 8; ++i)
                #pragma unroll
                for (int j = 0; j < 5; ++j)
                    acc[i][j] = __fmaf_rn(a[i], b[j], acc[i][j]);
        }
    }
    #pragma unroll
    for (int i = 0; i < 8; ++i) {
        const long m = m0 + ty*8 + i;
        #pragma unroll
        for (int j = 0; j < 4; ++j)
            z2[m*HH + n0 + tx*4 + j] = acc[i][j];
        z2[m*HH + n0 + 64 + tx] = acc[i][4];
    }
}

// ---------------------------------------------------------------------------
// K4: layer-2 membrane scan, strict fp32 np order ((0.95f*m)+z)+b2 (EXACT
// R5 semantics). mem2 in registers; writes s2r (d_out) + s2c (ws u8).
// ---------------------------------------------------------------------------
__global__ __launch_bounds__(256) void k_scan2(
    const float* __restrict__ z2, const float* __restrict__ b2,
    const float* __restrict__ thresh2, float* __restrict__ s2r,
    unsigned char* __restrict__ s2c)
{
    const int lid = blockIdx.x*256 + threadIdx.x;   // = b*HH + n
    const int n = lid % HH;
    const float b2v = b2[n];
    const float thv = thresh2[n];
    float m = 0.0f;
    for (int t = 0; t < TT; ++t) {
        const long idx = (long)t*BH + lid;
        const float m2 = __fadd_rn(
            __fadd_rn(__fmul_rn(0.95f, m), z2[idx]), b2v);
        const bool spk = m2 > thv;
        s2r[idx] = spk ? 1.0f : 0.0f;
        s2c[idx] = spk ? 1 : 0;
        m = spk ? 0.0f : m2;
    }
}

// ---------------------------------------------------------------------------
// K5: z3[m][o] = chain_k( s2[m][k]*W3[o][k] ) — strict ascending-k single
// chain (EXACT R5 layer-3 matmul semantics). One thread per m row, 10 accs;
// W3 accesses are wave-uniform -> scalar loads.
// ---------------------------------------------------------------------------
__global__ __launch_bounds__(256) void k_gemm3(
    const unsigned char* __restrict__ s2c, const float* __restrict__ W3,
    float* __restrict__ z3)
{
    const long m = blockIdx.x*256 + threadIdx.x;
    const unsigned char* row = s2c + m*HH;
    float acc[10] = {};
    for (int k0 = 0; k0 < HH; k0 += 16) {
        const uint4 v = *(const uint4*)(row + k0);
        const unsigned int d[4] = {v.x, v.y, v.z, v.w};
        #pragma unroll
        for (int w = 0; w < 4; ++w) {
            #pragma unroll
            for (int j = 0; j < 4; ++j) {
                const float sv = (float)((d[w] >> (8*j)) & 0xffu);
                const int k = k0 + w*4 + j;
                #pragma unroll
                for (int o = 0; o < 10; ++o)
                    acc[o] = __fmaf_rn(sv, W3[o*HH + k], acc[o]);
            }
        }
    }
    #pragma unroll
    for (int o = 0; o < 10; ++o)
        z3[m*OO + o] = acc[o];
}

// ---------------------------------------------------------------------------
// K6: layer-3 membrane scan, strict fp32 (EXACT R5 semantics). Writes s3r +
// out0 (d_out, write-only).
// ---------------------------------------------------------------------------
__global__ __launch_bounds__(256) void k_scan3(
    const float* __restrict__ z3, const float* __restrict__ b3,
    float* __restrict__ s3r, float* __restrict__ out0)
{
    const int gid = blockIdx.x*256 + threadIdx.x;   // = b*OO + o
    if (gid >= BB*OO) return;
    const int o = gid % OO;
    const float b3v = b3[o];
    float mem = 0.0f, cnt = 0.0f;
    for (int t = 0; t < TT; ++t) {
        const float m3 = __fadd_rn(
            __fadd_rn(__fmul_rn(0.95f, mem), z3[(long)t*BB*OO + gid]), b3v);
        const bool spk = m3 > 1.0f;
        s3r[(long)t*BB*OO + gid] = spk ? 1.0f : 0.0f;
        if (spk) cnt = __fadd_rn(cnt, 1.0f);
        mem = spk ? 0.0f : m3;
    }
    out0[gid] = cnt;
}

// ---------------------------------------------------------------------------
extern "C" void kernel_launch(void* const* d_in, const int* in_sizes, int n_in,
                              void* d_out, int out_size, void* d_ws, size_t ws_size,
                              hipStream_t stream)
{
    const float* x   = (const float*)d_in[0];
    const float* W1  = (const float*)d_in[1];
    const float* b1  = (const float*)d_in[2];
    const float* W2  = (const float*)d_in[3];
    const float* b2  = (const float*)d_in[4];
    const float* W3  = (const float*)d_in[5];
    const float* b3  = (const float*)d_in[6];
    const float* th1 = (const float*)d_in[7];
    const float* th2 = (const float*)d_in[8];

    float* out0 = (float*)d_out;                    // (B, OUT)   d_out is
    float* s1r  = out0 + BB*OO;                     // (T, B, H)  WRITE-ONLY
    float* s2r  = s1r + (long)TT*BH;                // (T, B, H)
    float* s3r  = s2r + (long)TT*BH;                // (T, B, OUT)

    // ws layout (total 204.8 MB == R5-proven budget):
    //   [0 .. 163.84 MB)   x1d f64  — dead after k_mem1, region reused:
    //        [0 .. 81.92 MB)      z2 f32  (written by k_gemm2 after k_mem1)
    //        [84 MB .. 85.03 MB)  z3 f32
    //   [163.84 .. 184.32 MB) s1c u8
    //   [184.32 .. 204.80 MB) s2c u8
    char* p = (char*)d_ws;
    double* x1d = (double*)p;
    float*  z2  = (float*)p;
    float*  z3  = (float*)(p + 84000000);
    unsigned char* s1c = (unsigned char*)(p + 163840000);
    unsigned char* s2c = s1c + (size_t)TT*BH;
    (void)ws_size;

    k_gemm1<<<dim3(200,10), dim3(256), 0, stream>>>(x, W1, b1, x1d);
    k_mem1 <<<dim3(1600),   dim3(256), 0, stream>>>(x1d, th1, s1c, s1r);
    k_gemm2<<<dim3(200,10), dim3(256), 0, stream>>>(s1c, W2, z2);
    k_scan2<<<dim3(1600),   dim3(256), 0, stream>>>(z2, b2, th2, s2r, s2c);
    k_gemm3<<<dim3(100),    dim3(256), 0, stream>>>(s2c, W3, z3);
    k_scan3<<<dim3(20),     dim3(256), 0, stream>>>(z3, b3, s3r, out0);
}